// Round 5
// baseline (2355.324 us; speedup 1.0000x reference)
//
#include <hip/hip_runtime.h>

#define NN     100000
#define EE     3200000
#define NF     512
#define HIDN   64
#define NCLS   64
#define ALPHA  0.1f

#define P       4                       // src partitions (2 XCDs each)
#define PSZ     25000                   // nodes per partition
#define NP      (NN * P)                // CSR key count
#define CHUNK   512
#define NB2     ((NP + CHUNK - 1) / CHUNK)   // 782 scan blocks

typedef unsigned short ushort_t;
typedef unsigned int   uint_t;

__device__ inline ushort_t f2bf(float f)   // fp32 -> bf16 RTN-even
{
    uint_t u = __float_as_uint(f);
    u += 0x7FFFu + ((u >> 16) & 1u);
    return (ushort_t)(u >> 16);
}
__device__ inline float bf2f(ushort_t b)
{
    return __uint_as_float(((uint_t)b) << 16);
}

// ---------------------------------------------------------------------------
// Tiled fp32 GEMM: C[nrows x 64] = act(A[nrows x K] @ B[K x 64])
// ---------------------------------------------------------------------------
template <bool RELU>
__global__ __launch_bounds__(256) void gemm_kernel(
    const float* __restrict__ A, const float* __restrict__ B,
    float* __restrict__ C, int nrows, int K)
{
    const int BK = 16;
    __shared__ float AsT[BK][68];
    __shared__ float Bs [BK][68];

    int tid = threadIdx.x;
    int tx  = tid & 15;
    int ty  = tid >> 4;
    int rowBase = blockIdx.x * 64;

    int arow = tid >> 2;
    int ak   = (tid & 3) * 4;
    int brow = tid >> 4;
    int bcol = (tid & 15) * 4;

    float acc[4][4] = {};

    for (int k0 = 0; k0 < K; k0 += BK) {
        float4 av;
        int gr = rowBase + arow;
        if (gr < nrows) av = *(const float4*)(A + (size_t)gr * K + k0 + ak);
        else            av = make_float4(0.f, 0.f, 0.f, 0.f);
        float4 bv = *(const float4*)(B + (size_t)(k0 + brow) * 64 + bcol);

        __syncthreads();
        AsT[ak + 0][arow] = av.x;
        AsT[ak + 1][arow] = av.y;
        AsT[ak + 2][arow] = av.z;
        AsT[ak + 3][arow] = av.w;
        *(float4*)&Bs[brow][bcol] = bv;
        __syncthreads();

#pragma unroll
        for (int kk = 0; kk < BK; ++kk) {
            float4 a = *(const float4*)&AsT[kk][ty * 4];
            float4 b = *(const float4*)&Bs [kk][tx * 4];
            acc[0][0] = fmaf(a.x, b.x, acc[0][0]);
            acc[0][1] = fmaf(a.x, b.y, acc[0][1]);
            acc[0][2] = fmaf(a.x, b.z, acc[0][2]);
            acc[0][3] = fmaf(a.x, b.w, acc[0][3]);
            acc[1][0] = fmaf(a.y, b.x, acc[1][0]);
            acc[1][1] = fmaf(a.y, b.y, acc[1][1]);
            acc[1][2] = fmaf(a.y, b.z, acc[1][2]);
            acc[1][3] = fmaf(a.y, b.w, acc[1][3]);
            acc[2][0] = fmaf(a.z, b.x, acc[2][0]);
            acc[2][1] = fmaf(a.z, b.y, acc[2][1]);
            acc[2][2] = fmaf(a.z, b.z, acc[2][2]);
            acc[2][3] = fmaf(a.z, b.w, acc[2][3]);
            acc[3][0] = fmaf(a.w, b.x, acc[3][0]);
            acc[3][1] = fmaf(a.w, b.y, acc[3][1]);
            acc[3][2] = fmaf(a.w, b.z, acc[3][2]);
            acc[3][3] = fmaf(a.w, b.w, acc[3][3]);
        }
    }

#pragma unroll
    for (int i = 0; i < 4; ++i) {
        int r = rowBase + ty * 4 + i;
        if (r < nrows) {
            float4 o;
            o.x = acc[i][0]; o.y = acc[i][1]; o.z = acc[i][2]; o.w = acc[i][3];
            if (RELU) {
                o.x = fmaxf(o.x, 0.f); o.y = fmaxf(o.y, 0.f);
                o.z = fmaxf(o.z, 0.f); o.w = fmaxf(o.w, 0.f);
            }
            *(float4*)(C + (size_t)r * 64 + tx * 4) = o;
        }
    }
}

// ---------------------------------------------------------------------------
// CSR construction, keyed by (dst*4 + src_partition)
// ---------------------------------------------------------------------------
__global__ __launch_bounds__(256) void zero_kernel(int* __restrict__ p, int n)
{
    int i = blockIdx.x * 256 + threadIdx.x;
    if (i < n) p[i] = 0;
}

__global__ __launch_bounds__(256) void count_kernel(const int* __restrict__ src,
                                                    const int* __restrict__ dst,
                                                    int* __restrict__ deg)
{
    int e = blockIdx.x * 256 + threadIdx.x;
    if (e < EE) {
        int k = (uint_t)src[e] / PSZ;
        atomicAdd(&deg[dst[e] * P + k], 1);
    }
}

__global__ __launch_bounds__(256) void scanA_kernel(const int* __restrict__ deg,
                                                    int* __restrict__ bsum)
{
    int b = blockIdx.x, t = threadIdx.x;
    int i = b * CHUNK + t * 2;
    int v = 0;
    if (i < NP)     v += deg[i];
    if (i + 1 < NP) v += deg[i + 1];
    __shared__ int sm[256];
    sm[t] = v;
    __syncthreads();
    for (int o = 128; o > 0; o >>= 1) {
        if (t < o) sm[t] += sm[t + o];
        __syncthreads();
    }
    if (t == 0) bsum[b] = sm[0];
}

// scans NB2 (<=1024) block sums with 256 threads x 4 items
__global__ __launch_bounds__(256) void scanB_kernel(const int* __restrict__ bsum,
                                                    int* __restrict__ bbase,
                                                    int* __restrict__ offs)
{
    int t = threadIdx.x;
    int v[4];
    int tot = 0;
#pragma unroll
    for (int j = 0; j < 4; ++j) {
        int idx = t * 4 + j;
        v[j] = (idx < NB2) ? bsum[idx] : 0;
        tot += v[j];
    }
    __shared__ int sm[256];
    sm[t] = tot;
    __syncthreads();
    for (int o = 1; o < 256; o <<= 1) {
        int u = (t >= o) ? sm[t - o] : 0;
        __syncthreads();
        sm[t] += u;
        __syncthreads();
    }
    int run = sm[t] - tot;
#pragma unroll
    for (int j = 0; j < 4; ++j) {
        int idx = t * 4 + j;
        if (idx < NB2) bbase[idx] = run;
        run += v[j];
    }
    if (t == 0) offs[NP] = EE;
}

__global__ __launch_bounds__(256) void scanC_kernel(const int* __restrict__ deg,
                                                    const int* __restrict__ bbase,
                                                    int* __restrict__ offs,
                                                    int* __restrict__ cursor)
{
    int b = blockIdx.x, t = threadIdx.x;
    int i0 = b * CHUNK + t * 2;
    int d0 = (i0 < NP)     ? deg[i0]     : 0;
    int d1 = (i0 + 1 < NP) ? deg[i0 + 1] : 0;
    int local = d0 + d1;
    __shared__ int sm[256];
    sm[t] = local;
    __syncthreads();
    for (int o = 1; o < 256; o <<= 1) {
        int u = (t >= o) ? sm[t - o] : 0;
        __syncthreads();
        sm[t] += u;
        __syncthreads();
    }
    int excl = sm[t] - local + bbase[b];
    if (i0 < NP)     { offs[i0]     = excl;      cursor[i0]     = excl;      }
    if (i0 + 1 < NP) { offs[i0 + 1] = excl + d0; cursor[i0 + 1] = excl + d0; }
}

__global__ __launch_bounds__(256) void scatter_kernel(
    const int* __restrict__ src, const int* __restrict__ dst,
    const float* __restrict__ w, int* cursor, int2* __restrict__ csr)
{
    int e = blockIdx.x * 256 + threadIdx.x;
    if (e >= EE) return;
    int s = src[e];
    int k = (uint_t)s / PSZ;
    int pos = atomicAdd(&cursor[dst[e] * P + k], 1);
    csr[pos] = make_int2(s, __float_as_int(w[e]));
}

// z0 (fp32) -> z0b (bf16) and zb_init (bf16)
__global__ __launch_bounds__(256) void cvt_kernel(const float* __restrict__ z0,
                                                  ushort_t* __restrict__ z0b,
                                                  ushort_t* __restrict__ zinit)
{
    int i = (blockIdx.x * 256 + threadIdx.x) * 4;
    if (i >= NN * 64) return;
    float4 v = *(const float4*)(z0 + i);
    ushort4 o;
    o.x = f2bf(v.x); o.y = f2bf(v.y); o.z = f2bf(v.z); o.w = f2bf(v.w);
    *(ushort4*)(z0b + i) = o;
    *(ushort4*)(zinit + i) = o;
}

// ---------------------------------------------------------------------------
// Partitioned propagation.
// Sub-pass: 100000 blocks; xcd = blockIdx&7 picks partition k = xcd>>1, so
// (if blockIdx%8 round-robins XCDs) gathers stay in a 3.2MB L2-resident slice.
// Every (node,k) is covered exactly once regardless of mapping (correctness
// is mapping-independent; only locality depends on it).
// ---------------------------------------------------------------------------
__global__ __launch_bounds__(256) void subpass_kernel(
    const ushort_t* __restrict__ zin, ushort_t* __restrict__ p01,
    ushort_t* __restrict__ p23, const int* __restrict__ offs,
    const int2* __restrict__ csr)
{
    int b    = blockIdx.x;
    int xcd  = b & 7;
    int k    = xcd >> 1;
    int sub  = xcd & 1;
    int bq   = b >> 3;
    int wid  = threadIdx.x >> 6;
    int lane = threadIdx.x & 63;
    int node = (bq * 2 + sub) * 4 + wid;     // < 100000 by construction

    int key = node * P + k;
    int beg = offs[key];
    int end = offs[key + 1];

    float acc = 0.f;
    int j = beg;
    for (; j + 4 <= end; j += 4) {
        int2 e0 = csr[j], e1 = csr[j + 1], e2 = csr[j + 2], e3 = csr[j + 3];
        float v0 = bf2f(zin[(size_t)e0.x * 64 + lane]);
        float v1 = bf2f(zin[(size_t)e1.x * 64 + lane]);
        float v2 = bf2f(zin[(size_t)e2.x * 64 + lane]);
        float v3 = bf2f(zin[(size_t)e3.x * 64 + lane]);
        acc = fmaf(__int_as_float(e0.y), v0, acc);
        acc = fmaf(__int_as_float(e1.y), v1, acc);
        acc = fmaf(__int_as_float(e2.y), v2, acc);
        acc = fmaf(__int_as_float(e3.y), v3, acc);
    }
    for (; j < end; ++j) {
        int2 e = csr[j];
        acc = fmaf(__int_as_float(e.y), bf2f(zin[(size_t)e.x * 64 + lane]), acc);
    }

    ushort_t* pout = (k < 2) ? p01 : p23;
    size_t idx = (size_t)(k & 1) * NN * 64 + (size_t)node * 64 + lane;
    pout[idx] = f2bf(acc);
}

// Reduce: z_next = sum partials + alpha*z0 (bf16), or final fp32 log_softmax.
template <bool LSM>
__global__ __launch_bounds__(256) void reduce_kernel(
    const ushort_t* __restrict__ p01, const ushort_t* __restrict__ p23,
    const ushort_t* __restrict__ z0b, ushort_t* __restrict__ zout_b,
    float* __restrict__ zout_f)
{
    int node = blockIdx.x * 4 + (threadIdx.x >> 6);
    int lane = threadIdx.x & 63;
    size_t idx = (size_t)node * 64 + lane;
    const size_t S = (size_t)NN * 64;

    float out = bf2f(p01[idx]) + bf2f(p01[S + idx])
              + bf2f(p23[idx]) + bf2f(p23[S + idx])
              + ALPHA * bf2f(z0b[idx]);

    if (LSM) {
        float m = out;
#pragma unroll
        for (int o = 32; o > 0; o >>= 1) m = fmaxf(m, __shfl_xor(m, o, 64));
        float e = __expf(out - m);
        float s = e;
#pragma unroll
        for (int o = 32; o > 0; o >>= 1) s += __shfl_xor(s, o, 64);
        zout_f[idx] = (out - m) - __logf(s);
    } else {
        zout_b[idx] = f2bf(out);
    }
}

// ---------------------------------------------------------------------------
// Direct (fallback) propagation: wave per node over its full contiguous edge
// range [offs[n*4], offs[n*4+4]). FINAL writes z10 in-place into z0b.
// ---------------------------------------------------------------------------
template <bool FINAL>
__global__ __launch_bounds__(256) void direct_kernel(
    const ushort_t* __restrict__ zin, ushort_t* __restrict__ z0b,
    ushort_t* __restrict__ zout, const int* __restrict__ offs,
    const int2* __restrict__ csr)
{
    int gid  = blockIdx.x * 256 + threadIdx.x;
    int node = gid >> 6;
    int lane = gid & 63;
    if (node >= NN) return;

    int beg = offs[node * P];
    int end = offs[node * P + P];
    float acc = 0.f;
    int j = beg;
    for (; j + 8 <= end; j += 8) {
        int2 e0 = csr[j],     e1 = csr[j + 1], e2 = csr[j + 2], e3 = csr[j + 3];
        int2 e4 = csr[j + 4], e5 = csr[j + 5], e6 = csr[j + 6], e7 = csr[j + 7];
        float v0 = bf2f(zin[(size_t)e0.x * 64 + lane]);
        float v1 = bf2f(zin[(size_t)e1.x * 64 + lane]);
        float v2 = bf2f(zin[(size_t)e2.x * 64 + lane]);
        float v3 = bf2f(zin[(size_t)e3.x * 64 + lane]);
        float v4 = bf2f(zin[(size_t)e4.x * 64 + lane]);
        float v5 = bf2f(zin[(size_t)e5.x * 64 + lane]);
        float v6 = bf2f(zin[(size_t)e6.x * 64 + lane]);
        float v7 = bf2f(zin[(size_t)e7.x * 64 + lane]);
        acc = fmaf(__int_as_float(e0.y), v0, acc);
        acc = fmaf(__int_as_float(e1.y), v1, acc);
        acc = fmaf(__int_as_float(e2.y), v2, acc);
        acc = fmaf(__int_as_float(e3.y), v3, acc);
        acc = fmaf(__int_as_float(e4.y), v4, acc);
        acc = fmaf(__int_as_float(e5.y), v5, acc);
        acc = fmaf(__int_as_float(e6.y), v6, acc);
        acc = fmaf(__int_as_float(e7.y), v7, acc);
    }
    for (; j < end; ++j) {
        int2 e = csr[j];
        acc = fmaf(__int_as_float(e.y), bf2f(zin[(size_t)e.x * 64 + lane]), acc);
    }

    size_t idx = (size_t)node * 64 + lane;
    float out = fmaf(ALPHA, bf2f(z0b[idx]), acc);
    if (FINAL) z0b[idx] = f2bf(out);     // in-place, same element only: race-free
    else       zout[idx] = f2bf(out);
}

// log_softmax: reads bf16 z10, writes fp32 to d_out (disjoint buffers)
__global__ __launch_bounds__(256) void lsm_kernel(const ushort_t* __restrict__ z,
                                                  float* __restrict__ out)
{
    int node = blockIdx.x * 4 + (threadIdx.x >> 6);
    int lane = threadIdx.x & 63;
    size_t idx = (size_t)node * 64 + lane;
    float v = bf2f(z[idx]);
    float m = v;
#pragma unroll
    for (int o = 32; o > 0; o >>= 1) m = fmaxf(m, __shfl_xor(m, o, 64));
    float e = __expf(v - m);
    float s = e;
#pragma unroll
    for (int o = 32; o > 0; o >>= 1) s += __shfl_xor(s, o, 64);
    out[idx] = (v - m) - __logf(s);
}

// ---------------------------------------------------------------------------
extern "C" void kernel_launch(void* const* d_in, const int* in_sizes, int n_in,
                              void* d_out, int out_size, void* d_ws, size_t ws_size,
                              hipStream_t stream)
{
    const float* x  = (const float*)d_in[0];
    const int*   ei = (const int*)  d_in[1];
    const float* ew = (const float*)d_in[2];
    const float* W1 = (const float*)d_in[3];
    const float* W2 = (const float*)d_in[4];
    const int* src = ei;
    const int* dst = ei + EE;

    char* ws = (char*)d_ws;
    size_t off = 0;
    auto alloc = [&](size_t bytes) -> char* {
        char* p = ws + off;
        off += (bytes + 255) & ~(size_t)255;
        return p;
    };

    const size_t ZB = (size_t)NN * 64;               // elements per z buffer

    float*    h     = (float*)   alloc(ZB * 4);      // 25.6 MB; -> csr (EE*8 == same size)
    float*    z0f   = (float*)   alloc(ZB * 4);      // 25.6 MB; -> p01 after cvt
    ushort_t* z0b   = (ushort_t*)alloc(ZB * 2);      // 12.8 MB
    int*      deg   = (int*)     alloc((size_t)NP * 4);
    int*      offs  = (int*)     alloc((size_t)(NP + 1) * 4);
    int*      cur_  = (int*)     alloc((size_t)NP * 4);
    int*      bsum  = (int*)     alloc((size_t)NB2 * 4);
    int*      bbase = (int*)     alloc((size_t)NB2 * 4);

    bool partitioned = (off + ZB * 4 + 256) <= ws_size;
    ushort_t* p23 = partitioned ? (ushort_t*)alloc(ZB * 4) : nullptr;  // 25.6 MB
    ushort_t* p01 = (ushort_t*)z0f;                  // reuses z0f region post-cvt

    int2* csr = (int2*)h;                            // h dead after GEMM2
    ushort_t* zb0 = (ushort_t*)d_out;                // z ping-pong hosted in d_out
    ushort_t* zb1 = zb0 + ZB;

    // feature transform
    gemm_kernel<true ><<<(NN + 63) / 64, 256, 0, stream>>>(x, W1, h, NN, NF);
    gemm_kernel<false><<<(NN + 63) / 64, 256, 0, stream>>>(h, W2, z0f, NN, HIDN);

    // CSR build keyed by (dst, src_partition)
    zero_kernel<<<(NP + 255) / 256, 256, 0, stream>>>(deg, NP);
    count_kernel<<<EE / 256, 256, 0, stream>>>(src, dst, deg);
    scanA_kernel<<<NB2, 256, 0, stream>>>(deg, bsum);
    scanB_kernel<<<1, 256, 0, stream>>>(bsum, bbase, offs);
    scanC_kernel<<<NB2, 256, 0, stream>>>(deg, bbase, offs, cur_);
    scatter_kernel<<<EE / 256, 256, 0, stream>>>(src, dst, ew, cur_, csr);

    // z_init = z0 (bf16); also keep bf16 z0 copy (z0f dead after this)
    cvt_kernel<<<(NN * 64 / 4 + 255) / 256, 256, 0, stream>>>(z0f, z0b, zb0);

    if (partitioned) {
        const ushort_t* cur = zb0;
        ushort_t* nxt = zb1;
        for (int it = 0; it < 10; ++it) {
            subpass_kernel<<<NN, 256, 0, stream>>>(cur, p01, p23, offs, csr);
            if (it < 9) {
                reduce_kernel<false><<<NN / 4, 256, 0, stream>>>(
                    p01, p23, z0b, nxt, nullptr);
                ushort_t* t = (ushort_t*)cur; cur = nxt; nxt = t;
            } else {
                reduce_kernel<true><<<NN / 4, 256, 0, stream>>>(
                    p01, p23, z0b, nullptr, (float*)d_out);
            }
        }
    } else {
        const ushort_t* cur = zb0;
        ushort_t* nxt = zb1;
        for (int it = 0; it < 9; ++it) {
            direct_kernel<false><<<(NN * 64) / 256, 256, 0, stream>>>(
                cur, z0b, nxt, offs, csr);
            ushort_t* t = (ushort_t*)cur; cur = nxt; nxt = t;
        }
        // final: z10 -> z0b in place (d_out regions must not be gather-read
        // while d_out is being written), then log_softmax to d_out.
        direct_kernel<true><<<(NN * 64) / 256, 256, 0, stream>>>(
            cur, z0b, nullptr, offs, csr);
        lsm_kernel<<<NN / 4, 256, 0, stream>>>(z0b, (float*)d_out);
    }
}